// Round 7
// baseline (151.520 us; speedup 1.0000x reference)
//
#include <hip/hip_runtime.h>
#include <hip/hip_bf16.h>
#include <stdint.h>

// B=32768 queries, M=4096 memory rows, D=128.
//   logits = Q @ M^T ; attn = softmax(logits) ; out = attn @ M
// Flash-style fused kernel. bf16x3-split MFMA QK^T (near-fp32), bf16 PV.
// v7: v6 + one-tile PV pipeline (carry pf0/pf1, 8 regs) + tri-buffered LDS.
// Each iteration issues QK(i)+PV(i-1) = 32 back-to-back MFMAs (independent
// chains) so the matrix pipe runs dense; softmax(i) sits at iteration end
// where the co-resident block's waves cover it. Tri-buffer (3x24KB=72KB,
// 2 blocks/CU = 144KB <= 160KB) lets STAGE(i+1) proceed while PV reads
// tile i-1's V fragments. Register peak ~248 unified -> still 2 blocks/CU.

typedef float   f32x16 __attribute__((ext_vector_type(16)));
typedef short   bf16x8 __attribute__((ext_vector_type(8)));
typedef uint32_t u32;

#define AS1 __attribute__((address_space(1)))
#define AS3 __attribute__((address_space(3)))

#define D_DIM 128
#define B_ROWS 32768
#define TILE_HW 12288     // halfwords per 32-row tile: [khi 4096|klo 4096|v 4096]
#define HALF_TILES 64     // tiles per block

#if __has_builtin(__builtin_amdgcn_exp2f)
#define EXP2F(x) __builtin_amdgcn_exp2f(x)
#else
#define EXP2F(x) exp2f(x)
#endif

__device__ __forceinline__ uint16_t f32_to_bf16_rne(float x) {
    u32 u = __float_as_uint(x);
    u32 r = u + 0x7fffu + ((u >> 16) & 1u);
    return (uint16_t)(r >> 16);
}
__device__ __forceinline__ float bf16_to_f32(uint16_t h) {
    return __uint_as_float(((u32)h) << 16);
}

// ---------------------------------------------------------------------------
// Prep: memory -> interleaved fragment-linear bf16 tiles in d_ws.
// Per tile mt (24576 B): [0,8K) khi frags, [8K,16K) klo frags, [16K,24K) v frags.
// ---------------------------------------------------------------------------
__global__ void prep_frags(const float* __restrict__ mem,
                           uint16_t* __restrict__ kv) {
    int t = blockIdx.x * blockDim.x + threadIdx.x;  // 0..65535
    int lane = t & 63;
    int fi = t >> 6;                                // 0..1023
    int f8 = fi & 7, mt = fi >> 3;
    size_t base = (size_t)mt * TILE_HW;
    {   // K fragment (hi/lo split)
        int m  = mt * 32 + (lane & 31);
        int d0 = f8 * 16 + (lane >> 5) * 8;
        const float* src = mem + (size_t)m * D_DIM + d0;
        #pragma unroll
        for (int e = 0; e < 8; ++e) {
            float x = src[e];
            uint16_t hb = f32_to_bf16_rne(x);
            kv[base + f8 * 512 + lane * 8 + e] = hb;
            kv[base + 4096 + f8 * 512 + lane * 8 + e] =
                f32_to_bf16_rne(x - bf16_to_f32(hb));
        }
    }
    {   // V^T fragment (plain bf16)
        int dt = fi & 3, ks = (fi >> 2) & 1;
        int d  = dt * 32 + (lane & 31);
        int m0 = mt * 32 + ks * 16 + (lane >> 5) * 8;
        #pragma unroll
        for (int e = 0; e < 8; ++e)
            kv[base + 8192 + f8 * 512 + lane * 8 + e] =
                f32_to_bf16_rne(mem[(size_t)(m0 + e) * D_DIM + d]);
    }
}

// ---------------------------------------------------------------------------
// Main kernel: 512 blocks x 256 threads (4 waves). Block bx: q-chunk bx>>1,
// memory half bx&1 (64 tiles). LDS tri-buffered 24KB tiles (72 KB).
// ---------------------------------------------------------------------------

#define STAGE(t_, wb_) do {                                                   \
    const char* g_ = (const char*)(kv + (size_t)(tilebase + (t_)) * TILE_HW); \
    char* l_ = (char*)&sbuf[wb_][0];                                          \
    _Pragma("unroll")                                                         \
    for (int j_ = 0; j_ < 6; ++j_) {                                          \
        int ch_ = wave * 6 + j_;                                              \
        __builtin_amdgcn_global_load_lds(                                     \
            (const AS1 char*)(g_ + ch_ * 1024 + lane * 16),                   \
            (AS3 char*)(l_ + ch_ * 1024), 16, 0, 0);                          \
    }                                                                         \
} while (0)

#define MFMA_BF16(a_, b_, c_) __builtin_amdgcn_mfma_f32_32x32x16_bf16(a_, b_, c_, 0, 0, 0)

// QK^T (bf16x3 split, 2 accumulator chains). Declares sh, sl.
#define QK(bp_)                                                               \
    f32x16 sh, sl;                                                            \
    _Pragma("unroll")                                                         \
    for (int i_ = 0; i_ < 16; ++i_) { sh[i_] = 0.f; sl[i_] = 0.f; }           \
    _Pragma("unroll")                                                         \
    for (int kk_ = 0; kk_ < 8; ++kk_) {                                       \
        bf16x8 kh_ = *(const bf16x8*)((bp_) + kk_ * 512);                     \
        bf16x8 kl_ = *(const bf16x8*)((bp_) + 4096 + kk_ * 512);              \
        sh = MFMA_BF16(kh_, qhi[kk_], sh);                                    \
        sl = MFMA_BF16(kh_, qlo[kk_], sl);                                    \
        sl = MFMA_BF16(kl_, qhi[kk_], sl);                                    \
    }

// PV for the PREVIOUS tile: V fragments from vp_, P fragments pf0/pf1.
#define PV(vp_) do {                                                          \
    bf16x8 vf_;                                                               \
    vf_ = *(const bf16x8*)((vp_) + 0*512); O0 = MFMA_BF16(vf_, pf0, O0);      \
    vf_ = *(const bf16x8*)((vp_) + 1*512); O1 = MFMA_BF16(vf_, pf0, O1);      \
    vf_ = *(const bf16x8*)((vp_) + 2*512); O2 = MFMA_BF16(vf_, pf0, O2);      \
    vf_ = *(const bf16x8*)((vp_) + 3*512); O3 = MFMA_BF16(vf_, pf0, O3);      \
    vf_ = *(const bf16x8*)((vp_) + 4*512); O0 = MFMA_BF16(vf_, pf1, O0);      \
    vf_ = *(const bf16x8*)((vp_) + 5*512); O1 = MFMA_BF16(vf_, pf1, O1);      \
    vf_ = *(const bf16x8*)((vp_) + 6*512); O2 = MFMA_BF16(vf_, pf1, O2);      \
    vf_ = *(const bf16x8*)((vp_) + 7*512); O3 = MFMA_BF16(vf_, pf1, O3);      \
} while (0)

// Online softmax on s (Sᵀ layout: q = lane&31) -> updates m_run/l_run/O
// scale, produces pf0/pf1 (bf16 B-frags) for the next iteration's PV.
#define SOFTMAX(s_) do {                                                      \
    float a0=fmaxf(s_[0],s_[1]),  a1=fmaxf(s_[2],s_[3]);                      \
    float a2=fmaxf(s_[4],s_[5]),  a3=fmaxf(s_[6],s_[7]);                      \
    float a4=fmaxf(s_[8],s_[9]),  a5=fmaxf(s_[10],s_[11]);                    \
    float a6=fmaxf(s_[12],s_[13]),a7=fmaxf(s_[14],s_[15]);                    \
    float tmax = fmaxf(fmaxf(fmaxf(a0,a1),fmaxf(a2,a3)),                      \
                       fmaxf(fmaxf(a4,a5),fmaxf(a6,a7)));                     \
    tmax = fmaxf(tmax, __shfl_xor(tmax, 32));                                 \
    if (__any(tmax > m_run + 8.0f)) {     /* defer-max (T13) */               \
        float mn = fmaxf(m_run, tmax);                                        \
        float fr = EXP2F(m_run - mn);                                         \
        m_run = mn; l_run *= fr;                                              \
        _Pragma("unroll")                                                     \
        for (int r_ = 0; r_ < 16; ++r_) {                                     \
            O0[r_] *= fr; O1[r_] *= fr; O2[r_] *= fr; O3[r_] *= fr;           \
        }                                                                     \
    }                                                                         \
    _Pragma("unroll")                                                         \
    for (int r_ = 0; r_ < 16; ++r_) s_[r_] = EXP2F(s_[r_] - m_run);           \
    { float q0s=s_[0]+s_[1],  q1s=s_[2]+s_[3],  q2s=s_[4]+s_[5],  q3s=s_[6]+s_[7];   \
      float q4s=s_[8]+s_[9],  q5s=s_[10]+s_[11],q6s=s_[12]+s_[13],q7s=s_[14]+s_[15]; \
      l_run += ((q0s+q1s)+(q2s+q3s)) + ((q4s+q5s)+(q6s+q7s)); }               \
    u32 c_[8];                                                                \
    _Pragma("unroll")                                                         \
    for (int j_ = 0; j_ < 8; ++j_)                                            \
        asm("v_cvt_pk_bf16_f32 %0, %1, %2"                                    \
            : "=v"(c_[j_]) : "v"(s_[2*j_]), "v"(s_[2*j_+1]));                 \
    asm("v_permlane32_swap_b32 %0, %1" : "+v"(c_[0]), "+v"(c_[2]));           \
    asm("v_permlane32_swap_b32 %0, %1" : "+v"(c_[1]), "+v"(c_[3]));           \
    asm("v_permlane32_swap_b32 %0, %1" : "+v"(c_[4]), "+v"(c_[6]));           \
    asm("v_permlane32_swap_b32 %0, %1" : "+v"(c_[5]), "+v"(c_[7]));           \
    { u32 w_[4] = {c_[0], c_[1], c_[2], c_[3]}; __builtin_memcpy(&pf0, w_, 16); } \
    { u32 w_[4] = {c_[4], c_[5], c_[6], c_[7]}; __builtin_memcpy(&pf1, w_, 16); } \
} while (0)

#define PSTORE_TILE(Ot_, t_) do {                                             \
    _Pragma("unroll")                                                         \
    for (int g_ = 0; g_ < 4; ++g_) {                                          \
        float4 v_ = { Ot_[4*g_+0], Ot_[4*g_+1], Ot_[4*g_+2], Ot_[4*g_+3] };   \
        int d_ = (t_) * 32 + 8 * g_ + 4 * hi32;                               \
        *(float4*)(prow + d_) = v_;                                           \
    }                                                                         \
} while (0)

__global__ __launch_bounds__(256, 2)
void attn_main(const float* __restrict__ qin,
               const uint16_t* __restrict__ kv,
               float* __restrict__ pout,      // [2][B_ROWS][128] partial O
               float2* __restrict__ pml) {    // [2][B_ROWS] (m, l)
    __shared__ uint16_t sbuf[3][TILE_HW];   // 3 x 24 KB = 72 KB

    const int lane = threadIdx.x & 63;
    const int wave = threadIdx.x >> 6;
    const int half = blockIdx.x & 1;
    const int tilebase = half * HALF_TILES;
    const int q0   = (blockIdx.x >> 1) * 128 + wave * 32;
    const int qrow = q0 + (lane & 31);
    const int hi32 = lane >> 5;

    // Q prep: scale by log2(e), split into bf16 hi/lo (B-frag of Sᵀ MFMA).
    bf16x8 qhi[8], qlo[8];
    {
        const float LOG2E = 1.44269504088896340736f;
        #pragma unroll
        for (int kk = 0; kk < 8; ++kk) {
            const float* src = qin + (size_t)qrow * D_DIM + kk * 16 + hi32 * 8;
            float4 a = *(const float4*)(src);
            float4 b = *(const float4*)(src + 4);
            float xs[8] = {a.x, a.y, a.z, a.w, b.x, b.y, b.z, b.w};
            #pragma unroll
            for (int e = 0; e < 8; ++e) {
                float x = xs[e] * LOG2E;
                uint16_t hb = f32_to_bf16_rne(x);
                qhi[kk][e] = (short)hb;
                qlo[kk][e] = (short)f32_to_bf16_rne(x - bf16_to_f32(hb));
            }
        }
    }

    f32x16 O0, O1, O2, O3;
    #pragma unroll
    for (int i = 0; i < 16; ++i) { O0[i]=0.f; O1[i]=0.f; O2[i]=0.f; O3[i]=0.f; }
    float m_run = -1e30f, l_run = 0.f;
    bf16x8 pf0, pf1;   // P fragments of tile i-1 (pipelined into iter i's PV)

    STAGE(0, 0);
    __syncthreads();

    // --- tile 0 prologue (no PV yet) ---
    {
        const uint16_t* bp = &sbuf[0][0] + lane * 8;
        STAGE(1, 1);
        QK(bp);
        f32x16 s = sh + sl;
        SOFTMAX(s);
        __syncthreads();
    }

    // --- steady state: iter i does QK(i) + PV(i-1) + softmax(i) ---
    #pragma unroll 1
    for (int i = 1; i < HALF_TILES; ++i) {
        const uint16_t* bp = &sbuf[i % 3][0] + lane * 8;
        const uint16_t* vp = &sbuf[(i - 1) % 3][0] + lane * 8 + 8192;
        if (i + 1 < HALF_TILES) STAGE(i + 1, (i + 1) % 3);
        QK(bp);           // 24 MFMA, chains sh/sl
        PV(vp);           // 8 MFMA, independent -> dense 32-MFMA burst
        f32x16 s = sh + sl;
        SOFTMAX(s);       // VALU tail, covered by co-resident block
        __syncthreads();
    }

    // --- drain: PV of last tile ---
    {
        const uint16_t* vp = &sbuf[(HALF_TILES - 1) % 3][0] + lane * 8 + 8192;
        PV(vp);
    }

    // ---- partial store (un-normalized O, plus m,l) ----
    l_run += __shfl_xor(l_run, 32);     // pair-lane partial sums
    float* prow = pout + ((size_t)half * B_ROWS + qrow) * D_DIM;
    PSTORE_TILE(O0, 0); PSTORE_TILE(O1, 1);
    PSTORE_TILE(O2, 2); PSTORE_TILE(O3, 3);
    if (lane < 32) {
        pml[(size_t)half * B_ROWS + qrow] = make_float2(m_run, l_run);
    }
}

// ---------------------------------------------------------------------------
// Merge: out = (P0*w0 + P1*w1) / (l0*w0 + l1*w1), w_i = exp2(m_i - max).
// One float4 per thread: 32768*32 float4s / 256 = 4096 blocks.
// ---------------------------------------------------------------------------
__global__ __launch_bounds__(256)
void merge_halves(const float* __restrict__ pout,
                  const float2* __restrict__ pml,
                  float* __restrict__ out) {
    int idx  = blockIdx.x * 256 + threadIdx.x;   // 0 .. 2^20-1
    int row  = idx >> 5;
    int c4   = idx & 31;
    float2 a = pml[row];
    float2 b = pml[B_ROWS + row];
    float mn = fmaxf(a.x, b.x);
    float wa = EXP2F(a.x - mn);
    float wb = EXP2F(b.x - mn);
    float rinv = 1.0f / (a.y * wa + b.y * wb);
    const float4* P0 = (const float4*)(pout + (size_t)row * D_DIM) + c4;
    const float4* P1 = (const float4*)(pout + ((size_t)B_ROWS + row) * D_DIM) + c4;
    float4 p0 = *P0, p1 = *P1;
    float4 v;
    v.x = (p0.x * wa + p1.x * wb) * rinv;
    v.y = (p0.y * wa + p1.y * wb) * rinv;
    v.z = (p0.z * wa + p1.z * wb) * rinv;
    v.w = (p0.w * wa + p1.w * wb) * rinv;
    *((float4*)(out + (size_t)row * D_DIM) + c4) = v;
}

extern "C" void kernel_launch(void* const* d_in, const int* in_sizes, int n_in,
                              void* d_out, int out_size, void* d_ws, size_t ws_size,
                              hipStream_t stream) {
    const float* local_stats = (const float*)d_in[0];   // [32768,128] f32
    const float* memory      = (const float*)d_in[1];   // [4096,128]  f32
    float* out = (float*)d_out;                         // [32768,128] f32

    // ws layout: kv frags 3MB | partial O 32MB | partial (m,l) 0.5MB
    uint16_t* kv  = (uint16_t*)d_ws;
    float*   pout = (float*)((char*)d_ws + 3 * 1024 * 1024);
    float2*  pml  = (float2*)((char*)pout + (size_t)2 * B_ROWS * D_DIM * 4);

    prep_frags<<<256, 256, 0, stream>>>(memory, kv);
    attn_main<<<512, 256, 0, stream>>>(local_stats, kv, pout, pml);
    merge_halves<<<4096, 256, 0, stream>>>(pout, pml, out);
}